// Round 6
// baseline (227.672 us; speedup 1.0000x reference)
//
#include <hip/hip_runtime.h>

#define NN 200000
#define NE 6400000
#define NB 800            // buckets: dst>>8, 256 nodes each
#define NWA 256           // scatter chunks (1 fat WG per CU)
#define CHUNK 25000       // NE / NWA exactly; single tile per WG
#define CHUNK4 6250       // CHUNK/4 int4 records
#define BUFCAP 44         // staged records per bucket (λ=31.25, σ=5.6 → +2.4σ; ovf parks rest)
#define CAPB 8704         // fixed per-bucket region in E (mean 8000, σ=89 → 8σ)
#define OVF 256           // overflow pair slots per WG (expected use ≈ 14)

// ws layout (4-byte units)
#define OFF_E    0                        // NB*CAPB = 6,963,200
#define OFF_C    6963200                  // NB: bucket cursors -> totals
#define OFF_RP   6964000                  // NN int2: packed {rowptr, degree} (spans old RP+DG)
#define OFF_DINV 7364000                  // (dead — kept for layout stability)
#define OFF_XS   7564000                  // 4*NN floats, w = dinv
#define OFF_HS2  8364000                  // 4*NN floats, w = dinv
// end: 9,164,000 ints = 36.7 MB

// Pass A: single-tile scatter, int4-vectorized edge loads (R5-proven form).
__global__ void __launch_bounds__(1024) k_scatter(const int* __restrict__ src,
                                                  const int* __restrict__ dst,
                                                  int* __restrict__ C,
                                                  int* __restrict__ E) {
    __shared__ int wbase[NB];
    __shared__ int cnt[NB];
    __shared__ int buf[NB * BUFCAP];   // 140.8 KB staging (1 WG/CU)
    __shared__ int ovf[2 * OVF];
    __shared__ int ovfn;
    int w = blockIdx.x, t = threadIdx.x;
    for (int b = t; b < NB; b += 1024) cnt[b] = 0;
    if (t == 0) ovfn = 0;
    __syncthreads();
    int lo = w * CHUNK;
    const int4* src4 = (const int4*)(src + lo);
    const int4* dst4 = (const int4*)(dst + lo);
    for (int i = t; i < CHUNK4; i += 1024) {
        int4 s4 = src4[i];
        int4 d4 = dst4[i];
#pragma unroll
        for (int q = 0; q < 4; ++q) {
            int s = (&s4.x)[q], d = (&d4.x)[q];
            int b = d >> 8;
            int rec = s | ((d & 255) << 18);
            int pos = atomicAdd(&cnt[b], 1);
            if (pos < BUFCAP) buf[b * BUFCAP + pos] = rec;
            else {
                int o = atomicAdd(&ovfn, 1);
                ovf[2 * o] = rec;
                ovf[2 * o + 1] = (b << 16) | pos;
            }
        }
    }
    __syncthreads();
    for (int b = t; b < NB; b += 1024)
        wbase[b] = b * CAPB + atomicAdd(&C[b], cnt[b]);
    __syncthreads();
    for (int idx = t; idx < NB * BUFCAP; idx += 1024) {
        int b = idx / BUFCAP, j = idx - b * BUFCAP;
        int c = cnt[b];
        if (j < (c < BUFCAP ? c : BUFCAP)) E[wbase[b] + j] = buf[idx];
    }
    for (int o = t; o < ovfn; o += 1024) {
        int rec = ovf[2 * o], bp = ovf[2 * o + 1];
        E[wbase[bp >> 16] + (bp & 0xFFFF)] = rec;
    }
}

// Pass B: per-bucket counting sort into CSR, int4 record I/O (R5-proven).
// NEW: emits packed RD{rp,dg} int2 and xs4 with w = dinv (dinv array dead).
__global__ void __launch_bounds__(512) k_sort(const float* __restrict__ x, int* __restrict__ E,
                       const int* __restrict__ C,
                       int2* __restrict__ RD,
                       float4* __restrict__ xs4) {
    __shared__ int stg[CAPB];          // 34.8 KB
    __shared__ int cnt[256];
    __shared__ int pos[256];
    int b = blockIdx.x, t = threadIdx.x;
    int lo = b * CAPB;
    int n = C[b];
    int n4 = n >> 2;
    if (t < 256) cnt[t] = 0;
    __syncthreads();
    const int4* E4 = (const int4*)(E + lo);
    for (int i = t; i < n4; i += 512) {
        int4 r = E4[i];
        ((int4*)stg)[i] = r;
        atomicAdd(&cnt[((unsigned)r.x) >> 18], 1);
        atomicAdd(&cnt[((unsigned)r.y) >> 18], 1);
        atomicAdd(&cnt[((unsigned)r.z) >> 18], 1);
        atomicAdd(&cnt[((unsigned)r.w) >> 18], 1);
    }
    for (int i = (n4 << 2) + t; i < n; i += 512) {
        int r = E[lo + i];
        stg[i] = r;
        atomicAdd(&cnt[((unsigned)r) >> 18], 1);
    }
    __syncthreads();
    if (t < 256) pos[t] = cnt[t];
    __syncthreads();
    for (int off = 1; off < 256; off <<= 1) {
        int v = 0;
        if (t < 256 && t >= off) v = pos[t - off];
        __syncthreads();
        if (t < 256) pos[t] += v;
        __syncthreads();
    }
    if (t < 256) {
        int c = cnt[t];
        int excl = pos[t] - c;
        int node = (b << 8) + t;
        if (node < NN) {
            RD[node] = make_int2(lo + excl, c);
            float di = rsqrtf(1.0f + (float)c);
            xs4[node] = make_float4(x[3 * node] * di, x[3 * node + 1] * di,
                                    x[3 * node + 2] * di, di);
        }
        cnt[t] = excl;   // becomes the scatter cursor
    }
    __syncthreads();
    for (int i = t; i < n4; i += 512) {
        int4 r = ((const int4*)stg)[i];
#pragma unroll
        for (int q = 0; q < 4; ++q) {
            int rec = (&r.x)[q];
            int slot = atomicAdd(&cnt[((unsigned)rec) >> 18], 1);
            E[lo + slot] = rec & 0x3FFFF;   // CSR: src only
        }
    }
    for (int i = (n4 << 2) + t; i < n; i += 512) {
        int rec = stg[i];
        int slot = atomicAdd(&cnt[((unsigned)rec) >> 18], 1);
        E[lo + slot] = rec & 0x3FFFF;
    }
}

// Pass C: layer-1 gather. NEW: 32 lanes per node — one E->xs4 dependent chain
// per lane for dg<=32 (55% of nodes; 2 covers 99.99%), 2x wave count for
// latency hiding. di rides in xs4.w; RD packed. All-lane dense epilogue.
__global__ void k_gather1(const int* __restrict__ E, const int2* __restrict__ RD,
                          const float4* __restrict__ xs4, const float* __restrict__ W1,
                          const float* __restrict__ b1, const float* __restrict__ W2,
                          float4* __restrict__ hs24) {
    int t = threadIdx.x;
    int seg = t >> 5, lane = t & 31;
    int n = blockIdx.x * 8 + seg;        // grid*8 == NN exactly
    int2 rd = RD[n];
    int rp = rd.x, dg = rd.y;
    float s0 = 0.f, s1 = 0.f, s2 = 0.f;
    if (lane < dg) {                      // primary chain: depth 1
        float4 m = xs4[E[rp + lane]];
        s0 = m.x; s1 = m.y; s2 = m.z;
    }
    for (int j = lane + 32; j < dg; j += 32) {   // rare tail
        float4 m = xs4[E[rp + j]];
        s0 += m.x; s1 += m.y; s2 += m.z;
    }
#pragma unroll
    for (int msk = 1; msk < 32; msk <<= 1) {
        s0 += __shfl_xor(s0, msk, 32);
        s1 += __shfl_xor(s1, msk, 32);
        s2 += __shfl_xor(s2, msk, 32);
    }
    float4 self = xs4[n];
    float di = self.w;
    float a0 = di * (s0 + self.x);
    float a1 = di * (s1 + self.y);
    float a2 = di * (s2 + self.z);
    int k = lane & 15;                    // both 16-halves compute redundantly
    float v = a0 * W1[k] + a1 * W1[16 + k] + a2 * W1[32 + k] + b1[k];
    v = v > 0.f ? v : 0.f;
    float o0 = v * W2[3 * k + 0];
    float o1 = v * W2[3 * k + 1];
    float o2 = v * W2[3 * k + 2];
#pragma unroll
    for (int msk = 1; msk < 16; msk <<= 1) {
        o0 += __shfl_xor(o0, msk, 16);
        o1 += __shfl_xor(o1, msk, 16);
        o2 += __shfl_xor(o2, msk, 16);
    }
    if (lane == 0)
        hs24[n] = make_float4(o0 * di, o1 * di, o2 * di, di);
}

// Pass D: layer-2 gather, 32 lanes per node + bias; di from hs24.w;
// LDS write-combined store (24 contiguous floats per block).
__global__ void k_gather2(const int* __restrict__ E, const int2* __restrict__ RD,
                          const float4* __restrict__ hs24, const float* __restrict__ b2,
                          float* __restrict__ out) {
    __shared__ float smo[24];
    int t = threadIdx.x;
    int seg = t >> 5, lane = t & 31;
    int n = blockIdx.x * 8 + seg;
    int2 rd = RD[n];
    int rp = rd.x, dg = rd.y;
    float s0 = 0.f, s1 = 0.f, s2 = 0.f;
    if (lane < dg) {
        float4 m = hs24[E[rp + lane]];
        s0 = m.x; s1 = m.y; s2 = m.z;
    }
    for (int j = lane + 32; j < dg; j += 32) {
        float4 m = hs24[E[rp + j]];
        s0 += m.x; s1 += m.y; s2 += m.z;
    }
#pragma unroll
    for (int msk = 1; msk < 32; msk <<= 1) {
        s0 += __shfl_xor(s0, msk, 32);
        s1 += __shfl_xor(s1, msk, 32);
        s2 += __shfl_xor(s2, msk, 32);
    }
    if (lane == 0) {
        float4 self = hs24[n];
        float di = self.w;
        smo[seg * 3 + 0] = di * (s0 + self.x) + b2[0];
        smo[seg * 3 + 1] = di * (s1 + self.y) + b2[1];
        smo[seg * 3 + 2] = di * (s2 + self.z) + b2[2];
    }
    __syncthreads();
    if (t < 24) out[(size_t)blockIdx.x * 24 + t] = smo[t];
}

extern "C" void kernel_launch(void* const* d_in, const int* in_sizes, int n_in,
                              void* d_out, int out_size, void* d_ws, size_t ws_size,
                              hipStream_t stream) {
    const float* x  = (const float*)d_in[0];
    const int* ei   = (const int*)d_in[1];
    const float* W1 = (const float*)d_in[2];
    const float* b1 = (const float*)d_in[3];
    const float* W2 = (const float*)d_in[4];
    const float* b2 = (const float*)d_in[5];
    const int* src = ei;
    const int* dst = ei + NE;
    float* ws = (float*)d_ws;
    int* wsi = (int*)d_ws;
    float* out = (float*)d_out;

    int* E      = wsi + OFF_E;
    int* C      = wsi + OFF_C;
    int2* RD    = (int2*)(wsi + OFF_RP);
    float4* xs4 = (float4*)(ws + OFF_XS);
    float4* hs24 = (float4*)(ws + OFF_HS2);

    hipMemsetAsync(C, 0, NB * sizeof(int), stream);
    k_scatter<<<NWA, 1024, 0, stream>>>(src, dst, C, E);
    k_sort<<<NB, 512, 0, stream>>>(x, E, C, RD, xs4);
    k_gather1<<<NN / 8, 256, 0, stream>>>(E, RD, xs4, W1, b1, W2, hs24);
    k_gather2<<<NN / 8, 256, 0, stream>>>(E, RD, hs24, b2, out);
}

// Round 7
// 212.702 us; speedup vs baseline: 1.0704x; 1.0704x over previous
//
#include <hip/hip_runtime.h>

#define NN 200000
#define NE 6400000
#define NB 800            // buckets: dst>>8, 256 nodes each
#define NWA 256           // scatter chunks (1 fat WG per CU)
#define CHUNK 25000       // NE / NWA exactly; single tile per WG
#define CHUNK4 6250       // CHUNK/4 int4 records
#define BUFCAP 44         // staged records per bucket (λ=31.25, σ=5.6 → +2.4σ; ovf parks rest)
#define CAPB 8704         // fixed per-bucket region in E (mean 8000, σ=89 → 8σ)
#define OVF 256           // overflow pair slots per WG (expected use ≈ 14)

// ws layout (4-byte units)
#define OFF_E    0                        // NB*CAPB = 6,963,200
#define OFF_C    6963200                  // NB: bucket cursors -> totals
#define OFF_RP   6964000                  // NN int2: packed {rowptr, degree}
#define OFF_XS   7564000                  // 4*NN floats, w = dinv
#define OFF_HS2  8364000                  // 4*NN floats, w = dinv
// end: 9,164,000 ints = 36.7 MB

// Pass A: single-tile scatter, int4-vectorized edge loads (R5-proven form).
__global__ void __launch_bounds__(1024) k_scatter(const int* __restrict__ src,
                                                  const int* __restrict__ dst,
                                                  int* __restrict__ C,
                                                  int* __restrict__ E) {
    __shared__ int wbase[NB];
    __shared__ int cnt[NB];
    __shared__ int buf[NB * BUFCAP];   // 140.8 KB staging (1 WG/CU)
    __shared__ int ovf[2 * OVF];
    __shared__ int ovfn;
    int w = blockIdx.x, t = threadIdx.x;
    for (int b = t; b < NB; b += 1024) cnt[b] = 0;
    if (t == 0) ovfn = 0;
    __syncthreads();
    int lo = w * CHUNK;
    const int4* src4 = (const int4*)(src + lo);
    const int4* dst4 = (const int4*)(dst + lo);
    for (int i = t; i < CHUNK4; i += 1024) {
        int4 s4 = src4[i];
        int4 d4 = dst4[i];
#pragma unroll
        for (int q = 0; q < 4; ++q) {
            int s = (&s4.x)[q], d = (&d4.x)[q];
            int b = d >> 8;
            int rec = s | ((d & 255) << 18);
            int pos = atomicAdd(&cnt[b], 1);
            if (pos < BUFCAP) buf[b * BUFCAP + pos] = rec;
            else {
                int o = atomicAdd(&ovfn, 1);
                ovf[2 * o] = rec;
                ovf[2 * o + 1] = (b << 16) | pos;
            }
        }
    }
    __syncthreads();
    for (int b = t; b < NB; b += 1024)
        wbase[b] = b * CAPB + atomicAdd(&C[b], cnt[b]);
    __syncthreads();
    for (int idx = t; idx < NB * BUFCAP; idx += 1024) {
        int b = idx / BUFCAP, j = idx - b * BUFCAP;
        int c = cnt[b];
        if (j < (c < BUFCAP ? c : BUFCAP)) E[wbase[b] + j] = buf[idx];
    }
    for (int o = t; o < ovfn; o += 1024) {
        int rec = ovf[2 * o], bp = ovf[2 * o + 1];
        E[wbase[bp >> 16] + (bp & 0xFFFF)] = rec;
    }
}

// Pass B: per-bucket counting sort into CSR, int4 record I/O (R5-proven).
// Emits packed RD{rp,dg} int2 and xs4 with w = dinv.
__global__ void __launch_bounds__(512) k_sort(const float* __restrict__ x, int* __restrict__ E,
                       const int* __restrict__ C,
                       int2* __restrict__ RD,
                       float4* __restrict__ xs4) {
    __shared__ int stg[CAPB];          // 34.8 KB
    __shared__ int cnt[256];
    __shared__ int pos[256];
    int b = blockIdx.x, t = threadIdx.x;
    int lo = b * CAPB;
    int n = C[b];
    int n4 = n >> 2;
    if (t < 256) cnt[t] = 0;
    __syncthreads();
    const int4* E4 = (const int4*)(E + lo);
    for (int i = t; i < n4; i += 512) {
        int4 r = E4[i];
        ((int4*)stg)[i] = r;
        atomicAdd(&cnt[((unsigned)r.x) >> 18], 1);
        atomicAdd(&cnt[((unsigned)r.y) >> 18], 1);
        atomicAdd(&cnt[((unsigned)r.z) >> 18], 1);
        atomicAdd(&cnt[((unsigned)r.w) >> 18], 1);
    }
    for (int i = (n4 << 2) + t; i < n; i += 512) {
        int r = E[lo + i];
        stg[i] = r;
        atomicAdd(&cnt[((unsigned)r) >> 18], 1);
    }
    __syncthreads();
    if (t < 256) pos[t] = cnt[t];
    __syncthreads();
    for (int off = 1; off < 256; off <<= 1) {
        int v = 0;
        if (t < 256 && t >= off) v = pos[t - off];
        __syncthreads();
        if (t < 256) pos[t] += v;
        __syncthreads();
    }
    if (t < 256) {
        int c = cnt[t];
        int excl = pos[t] - c;
        int node = (b << 8) + t;
        if (node < NN) {
            RD[node] = make_int2(lo + excl, c);
            float di = rsqrtf(1.0f + (float)c);
            xs4[node] = make_float4(x[3 * node] * di, x[3 * node + 1] * di,
                                    x[3 * node + 2] * di, di);
        }
        cnt[t] = excl;   // becomes the scatter cursor
    }
    __syncthreads();
    for (int i = t; i < n4; i += 512) {
        int4 r = ((const int4*)stg)[i];
#pragma unroll
        for (int q = 0; q < 4; ++q) {
            int rec = (&r.x)[q];
            int slot = atomicAdd(&cnt[((unsigned)rec) >> 18], 1);
            E[lo + slot] = rec & 0x3FFFF;   // CSR: src only
        }
    }
    for (int i = (n4 << 2) + t; i < n; i += 512) {
        int rec = stg[i];
        int slot = atomicAdd(&cnt[((unsigned)rec) >> 18], 1);
        E[lo + slot] = rec & 0x3FFFF;
    }
}

// Pass C: layer-1 gather, 16 lanes/node (R5-proven). NEW: flat 4-strip
// predicated gather — all E loads issue in parallel, then all xs4 loads;
// one waitcnt phase each instead of a serialized per-iteration chain.
// Covers dg<=64 (P(dg>64)~1e-8/node); tail loop for safety. Masked strips
// clamp to the row's last entry (uniform addr -> merges to 1 line request).
__global__ void k_gather1(const int* __restrict__ E, const int2* __restrict__ RD,
                          const float4* __restrict__ xs4, const float* __restrict__ W1,
                          const float* __restrict__ b1, const float* __restrict__ W2,
                          float4* __restrict__ hs24) {
    int t = threadIdx.x;
    int seg = t >> 4, lane = t & 15;
    int n = blockIdx.x * 16 + seg;        // grid*16 == NN exactly
    int2 rd = RD[n];
    int rp = rd.x, dg = rd.y;
    int last = rp + (dg > 0 ? dg - 1 : 0);
    int j0 = rp + lane;
    int e0 = E[j0 < last ? j0 : last];
    int e1 = E[j0 + 16 < last ? j0 + 16 : last];
    int e2 = E[j0 + 32 < last ? j0 + 32 : last];
    int e3 = E[j0 + 48 < last ? j0 + 48 : last];
    float4 m0 = xs4[e0];
    float4 m1 = xs4[e1];
    float4 m2 = xs4[e2];
    float4 m3 = xs4[e3];
    float f0 = (lane      < dg) ? 1.f : 0.f;
    float f1 = (lane + 16 < dg) ? 1.f : 0.f;
    float f2 = (lane + 32 < dg) ? 1.f : 0.f;
    float f3 = (lane + 48 < dg) ? 1.f : 0.f;
    float s0 = f0 * m0.x + f1 * m1.x + f2 * m2.x + f3 * m3.x;
    float s1 = f0 * m0.y + f1 * m1.y + f2 * m2.y + f3 * m3.y;
    float s2 = f0 * m0.z + f1 * m1.z + f2 * m2.z + f3 * m3.z;
    for (int j = lane + 64; j < dg; j += 16) {   // ~never
        float4 m = xs4[E[rp + j]];
        s0 += m.x; s1 += m.y; s2 += m.z;
    }
#pragma unroll
    for (int msk = 1; msk < 16; msk <<= 1) {
        s0 += __shfl_xor(s0, msk, 16);
        s1 += __shfl_xor(s1, msk, 16);
        s2 += __shfl_xor(s2, msk, 16);
    }
    float4 self = xs4[n];
    float di = self.w;
    float a0 = di * (s0 + self.x);
    float a1 = di * (s1 + self.y);
    float a2 = di * (s2 + self.z);
    int k = lane;
    float v = a0 * W1[k] + a1 * W1[16 + k] + a2 * W1[32 + k] + b1[k];
    v = v > 0.f ? v : 0.f;
    float o0 = v * W2[3 * k + 0];
    float o1 = v * W2[3 * k + 1];
    float o2 = v * W2[3 * k + 2];
#pragma unroll
    for (int msk = 1; msk < 16; msk <<= 1) {
        o0 += __shfl_xor(o0, msk, 16);
        o1 += __shfl_xor(o1, msk, 16);
        o2 += __shfl_xor(o2, msk, 16);
    }
    if (lane == 0)
        hs24[n] = make_float4(o0 * di, o1 * di, o2 * di, di);
}

// Pass D: layer-2 gather, 16 lanes/node, flat 4-strip gather + bias;
// LDS write-combined store (48 contiguous floats per block).
__global__ void k_gather2(const int* __restrict__ E, const int2* __restrict__ RD,
                          const float4* __restrict__ hs24, const float* __restrict__ b2,
                          float* __restrict__ out) {
    __shared__ float smo[48];
    int t = threadIdx.x;
    int seg = t >> 4, lane = t & 15;
    int n = blockIdx.x * 16 + seg;
    int2 rd = RD[n];
    int rp = rd.x, dg = rd.y;
    int last = rp + (dg > 0 ? dg - 1 : 0);
    int j0 = rp + lane;
    int e0 = E[j0 < last ? j0 : last];
    int e1 = E[j0 + 16 < last ? j0 + 16 : last];
    int e2 = E[j0 + 32 < last ? j0 + 32 : last];
    int e3 = E[j0 + 48 < last ? j0 + 48 : last];
    float4 m0 = hs24[e0];
    float4 m1 = hs24[e1];
    float4 m2 = hs24[e2];
    float4 m3 = hs24[e3];
    float f0 = (lane      < dg) ? 1.f : 0.f;
    float f1 = (lane + 16 < dg) ? 1.f : 0.f;
    float f2 = (lane + 32 < dg) ? 1.f : 0.f;
    float f3 = (lane + 48 < dg) ? 1.f : 0.f;
    float s0 = f0 * m0.x + f1 * m1.x + f2 * m2.x + f3 * m3.x;
    float s1 = f0 * m0.y + f1 * m1.y + f2 * m2.y + f3 * m3.y;
    float s2 = f0 * m0.z + f1 * m1.z + f2 * m2.z + f3 * m3.z;
    for (int j = lane + 64; j < dg; j += 16) {
        float4 m = hs24[E[rp + j]];
        s0 += m.x; s1 += m.y; s2 += m.z;
    }
#pragma unroll
    for (int msk = 1; msk < 16; msk <<= 1) {
        s0 += __shfl_xor(s0, msk, 16);
        s1 += __shfl_xor(s1, msk, 16);
        s2 += __shfl_xor(s2, msk, 16);
    }
    if (lane == 0) {
        float4 self = hs24[n];
        float di = self.w;
        smo[seg * 3 + 0] = di * (s0 + self.x) + b2[0];
        smo[seg * 3 + 1] = di * (s1 + self.y) + b2[1];
        smo[seg * 3 + 2] = di * (s2 + self.z) + b2[2];
    }
    __syncthreads();
    if (t < 48) out[(size_t)blockIdx.x * 48 + t] = smo[t];
}

extern "C" void kernel_launch(void* const* d_in, const int* in_sizes, int n_in,
                              void* d_out, int out_size, void* d_ws, size_t ws_size,
                              hipStream_t stream) {
    const float* x  = (const float*)d_in[0];
    const int* ei   = (const int*)d_in[1];
    const float* W1 = (const float*)d_in[2];
    const float* b1 = (const float*)d_in[3];
    const float* W2 = (const float*)d_in[4];
    const float* b2 = (const float*)d_in[5];
    const int* src = ei;
    const int* dst = ei + NE;
    float* ws = (float*)d_ws;
    int* wsi = (int*)d_ws;
    float* out = (float*)d_out;

    int* E      = wsi + OFF_E;
    int* C      = wsi + OFF_C;
    int2* RD    = (int2*)(wsi + OFF_RP);
    float4* xs4 = (float4*)(ws + OFF_XS);
    float4* hs24 = (float4*)(ws + OFF_HS2);

    hipMemsetAsync(C, 0, NB * sizeof(int), stream);
    k_scatter<<<NWA, 1024, 0, stream>>>(src, dst, C, E);
    k_sort<<<NB, 512, 0, stream>>>(x, E, C, RD, xs4);
    k_gather1<<<NN / 16, 256, 0, stream>>>(E, RD, xs4, W1, b1, W2, hs24);
    k_gather2<<<NN / 16, 256, 0, stream>>>(E, RD, hs24, b2, out);
}